// Round 16
// baseline (211.652 us; speedup 1.0000x reference)
//
#include <hip/hip_runtime.h>

#define B_ 128
#define N_ 64
#define T_ 1000
#define H_ 16

// ---------------- A: energy[b,i] = var(x[b,0,i,:], ddof=1) ----------------
__global__ __launch_bounds__(256) void k_energy(const float* __restrict__ x, float* __restrict__ energy) {
    int row = blockIdx.x;                       // b*64 + i
    const float* xr = x + (size_t)row * T_;
    float s = 0.f, s2 = 0.f;
    for (int t4 = threadIdx.x; t4 < 250; t4 += 256) {
        float4 v = ((const float4*)xr)[t4];
        s += v.x + v.y + v.z + v.w;
        s2 += v.x*v.x + v.y*v.y + v.z*v.z + v.w*v.w;
    }
    __shared__ float r1[256], r2[256];
    r1[threadIdx.x] = s; r2[threadIdx.x] = s2;
    __syncthreads();
    for (int off = 128; off > 0; off >>= 1) {
        if (threadIdx.x < off) {
            r1[threadIdx.x] += r1[threadIdx.x + off];
            r2[threadIdx.x] += r2[threadIdx.x + off];
        }
        __syncthreads();
    }
    if (threadIdx.x == 0) {
        float S = r1[0], S2 = r2[0];
        energy[row] = (S2 - S * S / (float)T_) / (float)(T_ - 1);
    }
}

// ------- C (+attn fused): rank-1 attention softmax in-block, then z_gcn ----
#define ZTC 128
__global__ __launch_bounds__(256) void k_zgcn(const float* __restrict__ energy,
        const float* __restrict__ q_w, const float* __restrict__ q_b,
        const float* __restrict__ k_w, const float* __restrict__ k_b,
        const float* __restrict__ x, float* __restrict__ zg,
        float* __restrict__ wmat_out, double* __restrict__ stats) {
    int b = blockIdx.y;
    int t0 = blockIdx.x * ZTC;
    int tid = threadIdx.x;
    if (blockIdx.x == 0 && b == 0 && tid < 163) stats[tid] = 0.0;
    __shared__ __attribute__((aligned(16))) float wsh[64 * 64];
    __shared__ __attribute__((aligned(16))) float xs[64][ZTC];
    __shared__ float en[64];
    float (*red1)[4] = (float(*)[4])&xs[0][0];   // scratch overlay (pre-staging)
    float (*red2)[4] = (float(*)[4])&xs[2][0];
    if (tid < 64) en[tid] = energy[b * 64 + tid];
    __syncthreads();
    float alpha = 0.f, beta = 0.f;
    #pragma unroll
    for (int hh = 0; hh < H_; ++hh) {
        alpha = fmaf(q_w[hh], k_w[hh], alpha);
        beta  = fmaf(q_b[hh], k_w[hh], beta);
    }
    int row = tid >> 2, q = tid & 3;
    float si = 0.25f * fmaf(alpha, en[row], beta);
    float vals[16];
    float m = -3.0e38f;
    #pragma unroll
    for (int k = 0; k < 16; ++k) {
        int j = q * 16 + k;
        float a = si * en[j];
        if (j == row) a = -3.0e38f;
        vals[k] = a;
        m = fmaxf(m, a);
    }
    red1[row][q] = m;
    __syncthreads();
    float m4 = fmaxf(fmaxf(red1[row][0], red1[row][1]), fmaxf(red1[row][2], red1[row][3]));
    float sum = 0.f;
    #pragma unroll
    for (int k = 0; k < 16; ++k) {
        float p = __expf(vals[k] - m4);
        vals[k] = p;
        sum += p;
    }
    red2[row][q] = sum;
    __syncthreads();
    float den = red2[row][0] + red2[row][1] + red2[row][2] + red2[row][3];
    float inv = 1.f / den;
    #pragma unroll
    for (int k = 0; k < 16; ++k) vals[k] *= inv;
    __syncthreads();                             // red scratch dead before xs staging
    #pragma unroll
    for (int k = 0; k < 16; ++k) wsh[row * 64 + q * 16 + k] = vals[k];
    if (blockIdx.x == 0) {
        float* wr = wmat_out + (size_t)b * 4096 + row * 64 + q * 16;
        ((float4*)wr)[0] = float4{vals[0],  vals[1],  vals[2],  vals[3]};
        ((float4*)wr)[1] = float4{vals[4],  vals[5],  vals[6],  vals[7]};
        ((float4*)wr)[2] = float4{vals[8],  vals[9],  vals[10], vals[11]};
        ((float4*)wr)[3] = float4{vals[12], vals[13], vals[14], vals[15]};
    }
    const float* xb = x + (size_t)b * 64 * T_;
    for (int i = tid; i < 2048; i += 256) {
        int jj = i >> 5;
        int c4 = i & 31;
        int tt = t0 + c4 * 4;
        float4 val;
        if (tt + 3 < T_) val = *(const float4*)(xb + jj * T_ + tt);
        else {
            val.x = (tt     < T_) ? xb[jj * T_ + tt]     : 0.f;
            val.y = (tt + 1 < T_) ? xb[jj * T_ + tt + 1] : 0.f;
            val.z = (tt + 2 < T_) ? xb[jj * T_ + tt + 2] : 0.f;
            val.w = (tt + 3 < T_) ? xb[jj * T_ + tt + 3] : 0.f;
        }
        *(float4*)&xs[jj][c4 * 4] = val;
    }
    __syncthreads();
    int gi = tid >> 5, gt = tid & 31;
    int ii0 = gi * 8, tt0 = gt * 4;
    float4 acc[8];
    #pragma unroll
    for (int r = 0; r < 8; ++r) acc[r] = float4{0.f, 0.f, 0.f, 0.f};
    for (int jj = 0; jj < 64; ++jj) {
        float4 xv = *(const float4*)&xs[jj][tt0];
        #pragma unroll
        for (int r = 0; r < 8; ++r) {
            float wv = wsh[(ii0 + r) * 64 + jj];
            acc[r].x += wv * xv.x; acc[r].y += wv * xv.y;
            acc[r].z += wv * xv.z; acc[r].w += wv * xv.w;
        }
    }
    int tt = t0 + tt0;
    #pragma unroll
    for (int r = 0; r < 8; ++r) {
        float4 res = *(const float4*)&xs[ii0 + r][tt0];
        acc[r].x += res.x; acc[r].y += res.y; acc[r].z += res.z; acc[r].w += res.w;
        float* dst = zg + (size_t)b * 64 * T_ + (size_t)(ii0 + r) * T_;
        if (tt + 3 < T_) {
            *(float4*)(dst + tt) = acc[r];
        } else {
            if (tt     < T_) dst[tt]     = acc[r].x;
            if (tt + 1 < T_) dst[tt + 1] = acc[r].y;
            if (tt + 2 < T_) dst[tt + 2] = acc[r].z;
            if (tt + 3 < T_) dst[tt + 3] = acc[r].w;
        }
    }
}

// ------- D: autocorr lags 0..14 + total sum + boundary corrections ---------
__global__ __launch_bounds__(256) void k_autocorr(const float* __restrict__ zg, double* __restrict__ stats) {
    __shared__ float rows[8][1070];             // stride-33 spans, conflict-free
    int row0 = blockIdx.x * 8;
    for (int idx = threadIdx.x; idx < 8 * 1070; idx += 256) {
        int rr = idx / 1070, j = idx - rr * 1070;
        rows[rr][j] = (j < T_) ? zg[(size_t)(row0 + rr) * T_ + j] : 0.f;
    }
    __syncthreads();
    int r = threadIdx.x >> 5, q = threadIdx.x & 31;
    const float* p = &rows[r][0];
    int t = q * 33;
    float w0=p[t+0], w1=p[t+1], w2=p[t+2], w3=p[t+3], w4=p[t+4], w5=p[t+5], w6=p[t+6],
          w7=p[t+7], w8=p[t+8], w9=p[t+9], w10=p[t+10], w11=p[t+11], w12=p[t+12], w13=p[t+13], w14;
    float a0=0.f,a1=0.f,a2=0.f,a3=0.f,a4=0.f,a5=0.f,a6=0.f,a7=0.f,a8=0.f,a9=0.f,
          a10=0.f,a11=0.f,a12=0.f,a13=0.f,a14=0.f, s1=0.f;
    #define ASTEP(wA,wB,wC,wD,wE,wF,wG,wH,wI,wJ,wK,wL,wM,wN,wO, off) { \
        wO = p[t + (off) + 14]; \
        s1 += wA; \
        a0  = fmaf(wA,wA,a0);  a1  = fmaf(wA,wB,a1);  a2  = fmaf(wA,wC,a2);  \
        a3  = fmaf(wA,wD,a3);  a4  = fmaf(wA,wE,a4);  a5  = fmaf(wA,wF,a5);  \
        a6  = fmaf(wA,wG,a6);  a7  = fmaf(wA,wH,a7);  a8  = fmaf(wA,wI,a8);  \
        a9  = fmaf(wA,wJ,a9);  a10 = fmaf(wA,wK,a10); a11 = fmaf(wA,wL,a11); \
        a12 = fmaf(wA,wM,a12); a13 = fmaf(wA,wN,a13); a14 = fmaf(wA,wO,a14); }
    #define AR0(o)  ASTEP(w0,w1,w2,w3,w4,w5,w6,w7,w8,w9,w10,w11,w12,w13,w14, o)
    #define AR1(o)  ASTEP(w1,w2,w3,w4,w5,w6,w7,w8,w9,w10,w11,w12,w13,w14,w0, o)
    #define AR2(o)  ASTEP(w2,w3,w4,w5,w6,w7,w8,w9,w10,w11,w12,w13,w14,w0,w1, o)
    #define AR3(o)  ASTEP(w3,w4,w5,w6,w7,w8,w9,w10,w11,w12,w13,w14,w0,w1,w2, o)
    #define AR4(o)  ASTEP(w4,w5,w6,w7,w8,w9,w10,w11,w12,w13,w14,w0,w1,w2,w3, o)
    #define AR5(o)  ASTEP(w5,w6,w7,w8,w9,w10,w11,w12,w13,w14,w0,w1,w2,w3,w4, o)
    #define AR6(o)  ASTEP(w6,w7,w8,w9,w10,w11,w12,w13,w14,w0,w1,w2,w3,w4,w5, o)
    #define AR7(o)  ASTEP(w7,w8,w9,w10,w11,w12,w13,w14,w0,w1,w2,w3,w4,w5,w6, o)
    #define AR8(o)  ASTEP(w8,w9,w10,w11,w12,w13,w14,w0,w1,w2,w3,w4,w5,w6,w7, o)
    #define AR9(o)  ASTEP(w9,w10,w11,w12,w13,w14,w0,w1,w2,w3,w4,w5,w6,w7,w8, o)
    #define AR10(o) ASTEP(w10,w11,w12,w13,w14,w0,w1,w2,w3,w4,w5,w6,w7,w8,w9, o)
    #define AR11(o) ASTEP(w11,w12,w13,w14,w0,w1,w2,w3,w4,w5,w6,w7,w8,w9,w10, o)
    #define AR12(o) ASTEP(w12,w13,w14,w0,w1,w2,w3,w4,w5,w6,w7,w8,w9,w10,w11, o)
    #define AR13(o) ASTEP(w13,w14,w0,w1,w2,w3,w4,w5,w6,w7,w8,w9,w10,w11,w12, o)
    #define AR14(o) ASTEP(w14,w0,w1,w2,w3,w4,w5,w6,w7,w8,w9,w10,w11,w12,w13, o)
    for (int mi = 0; mi < 2; ++mi) {
        AR0(0) AR1(1) AR2(2) AR3(3) AR4(4) AR5(5) AR6(6) AR7(7)
        AR8(8) AR9(9) AR10(10) AR11(11) AR12(12) AR13(13) AR14(14)
        t += 15;
    }
    AR0(0) AR1(1) AR2(2)                        // 33 total
    #undef ASTEP
    __syncthreads();
    float eacc = 0.f;
    int v = threadIdx.x;
    if (v < 147) {
        int mode, ia, ib;
        if (v < 105) { mode = 0; ia = v / 15; ib = ia + (v % 15); }
        else if (v < 133) {
            int idx = v - 105; int i = 0, len = 7;
            while (idx >= len) { idx -= len; ++i; --len; }
            mode = 2; ia = 993 + i; ib = 993 + i + idx;
        }
        else if (v < 140) { mode = 1; ia = 0; ib = v - 133; }
        else { mode = 1; ia = 993 + (v - 140); ib = 999; }
        for (int rr = 0; rr < 8; ++rr) {
            const float* zr = &rows[rr][0];
            float val;
            if (mode != 1) val = zr[ia] * zr[ib];
            else { val = 0.f; for (int i = ia; i <= ib; ++i) val += zr[i]; }
            eacc += val;
        }
    }
    __syncthreads();
    float* red = &rows[0][0];
    int tid = threadIdx.x;
    red[tid*17+0]=a0;  red[tid*17+1]=a1;  red[tid*17+2]=a2;  red[tid*17+3]=a3;
    red[tid*17+4]=a4;  red[tid*17+5]=a5;  red[tid*17+6]=a6;  red[tid*17+7]=a7;
    red[tid*17+8]=a8;  red[tid*17+9]=a9;  red[tid*17+10]=a10; red[tid*17+11]=a11;
    red[tid*17+12]=a12; red[tid*17+13]=a13; red[tid*17+14]=a14; red[tid*17+15]=s1;
    __syncthreads();
    for (int off = 128; off > 0; off >>= 1) {
        if (tid < off)
            for (int k = 0; k < 16; ++k) red[tid*17+k] += red[(tid+off)*17+k];
        __syncthreads();
    }
    if (tid < 16) atomicAdd(&stats[tid], (double)red[tid]);
    if (v < 147) atomicAdd(&stats[16 + v], (double)eacc);
}

// ------- F: finalize(in-block) + scalar conv from reg window + ELU + LIF ---
// 16 rows x 16 ch per block; T in 21 chunks of 48 (last 40); window = g[16]
// float4 regs from coalesced global loads (16 h-lanes/row share addresses).
__global__ __launch_bounds__(256) void k_scan(const float* __restrict__ zg,
        const double* __restrict__ stats, const float* __restrict__ conv_w,
        const float* __restrict__ gamma, const float* __restrict__ beta,
        float* __restrict__ zfeat) {
    int tid = threadIdx.x;
    int h = tid & 15, r = tid >> 4;
    int row0 = blockIdx.x * 16;
    __shared__ float scsh_s[256];
    if (tid < 16) {                             // finalize BN -> folded taps
        int hh = tid;
        const double M = (double)(B_ * N_) * (double)T_;
        double w[15];
        #pragma unroll
        for (int k = 0; k < 15; ++k) w[k] = (double)conv_w[hh * 15 + k];
        double SA = stats[15];
        const double* HP  = stats + 16;
        const double* TP  = stats + 16 + 105;
        const double* PRE = stats + 16 + 133;
        const double* SUF = stats + 16 + 140;
        double so = 0.0;
        #pragma unroll
        for (int k = 0; k < 15; ++k) {
            double U = SA;
            if (k < 7)      U -= SUF[k];
            else if (k > 7) U -= PRE[k - 8];
            so += w[k] * U;
        }
        double mean_o = so / M;
        double q = 0.0;
        #pragma unroll
        for (int k = 0; k < 15; ++k)
        #pragma unroll
        for (int k2 = 0; k2 < 15; ++k2) {
            int a = (k < k2) ? k : k2;
            int d = (k < k2) ? (k2 - k) : (k - k2);
            double G = stats[d];
            if (a >= 8)
                for (int i = 0; i <= a - 8; ++i) G -= HP[i * 15 + d];
            if (a + d <= 6)
                for (int i = a + 993; i <= 999 - d; ++i) {
                    int ip = i - 993;
                    G -= TP[ip * 7 - ip * (ip - 1) / 2 + d];
                }
            q += w[k] * w[k2] * G;
        }
        double var = q / M - mean_o * mean_o;
        double sc = (double)gamma[hh] / sqrt(var + 1e-5);
        scsh_s[240 + hh] = (float)((double)beta[hh] - mean_o * sc);
        #pragma unroll
        for (int k = 0; k < 15; ++k) scsh_s[hh * 15 + k] = (float)(w[k] * sc);
    }
    __syncthreads();
    float c0 = scsh_s[h*15+0],  c1 = scsh_s[h*15+1],  c2 = scsh_s[h*15+2],  c3 = scsh_s[h*15+3];
    float c4 = scsh_s[h*15+4],  c5 = scsh_s[h*15+5],  c6 = scsh_s[h*15+6],  c7 = scsh_s[h*15+7];
    float c8 = scsh_s[h*15+8],  c9 = scsh_s[h*15+9],  c10 = scsh_s[h*15+10], c11 = scsh_s[h*15+11];
    float c12 = scsh_s[h*15+12], c13 = scsh_s[h*15+13], c14 = scsh_s[h*15+14];
    float sh = scsh_s[240 + h];
    const float* zrow = zg + (size_t)(row0 + r) * T_;
    float u = 2.f, cnt = 0.f;
    float4 g[16];
    const float4 f4z = {0.f, 0.f, 0.f, 0.f};

    // window-relative float at index n (0..63): direct register access
    #define GF(n) ( (((n)&3)==0) ? g[(n)>>2].x \
                  : (((n)&3)==1) ? g[(n)>>2].y \
                  : (((n)&3)==2) ? g[(n)>>2].z \
                  :                g[(n)>>2].w )

    #define OUT(j) { \
        float o0 = fmaf(c0,GF((j)+1), fmaf(c3,GF((j)+4), fmaf(c6,GF((j)+7), fmaf(c9,GF((j)+10), fmaf(c12,GF((j)+13), sh))))); \
        float o1 = fmaf(c1,GF((j)+2), fmaf(c4,GF((j)+5), fmaf(c7,GF((j)+8), fmaf(c10,GF((j)+11), c13*GF((j)+14))))); \
        float o2 = fmaf(c2,GF((j)+3), fmaf(c5,GF((j)+6), fmaf(c8,GF((j)+9), fmaf(c11,GF((j)+12), c14*GF((j)+15))))); \
        float zz = (o0 + o1) + o2; \
        float pe = fmaxf(zz, 0.f) + __expf(fminf(zz, 0.f)); \
        u = fmaf(0.5f, u, pe); \
        float sp = (u > 2.5f) ? 1.f : 0.f; \
        cnt += sp; u = fmaf(-0.5f, sp, u); }

    #define OUTS48 \
        OUT(0)  OUT(1)  OUT(2)  OUT(3)  OUT(4)  OUT(5)  OUT(6)  OUT(7) \
        OUT(8)  OUT(9)  OUT(10) OUT(11) OUT(12) OUT(13) OUT(14) OUT(15) \
        OUT(16) OUT(17) OUT(18) OUT(19) OUT(20) OUT(21) OUT(22) OUT(23) \
        OUT(24) OUT(25) OUT(26) OUT(27) OUT(28) OUT(29) OUT(30) OUT(31) \
        OUT(32) OUT(33) OUT(34) OUT(35) OUT(36) OUT(37) OUT(38) OUT(39) \
        OUT(40) OUT(41) OUT(42) OUT(43) OUT(44) OUT(45) OUT(46) OUT(47)

    #define OUTS40 \
        OUT(0)  OUT(1)  OUT(2)  OUT(3)  OUT(4)  OUT(5)  OUT(6)  OUT(7) \
        OUT(8)  OUT(9)  OUT(10) OUT(11) OUT(12) OUT(13) OUT(14) OUT(15) \
        OUT(16) OUT(17) OUT(18) OUT(19) OUT(20) OUT(21) OUT(22) OUT(23) \
        OUT(24) OUT(25) OUT(26) OUT(27) OUT(28) OUT(29) OUT(30) OUT(31) \
        OUT(32) OUT(33) OUT(34) OUT(35) OUT(36) OUT(37) OUT(38) OUT(39)

    {   // head chunk c=0: window base -8, g0/g1 zero-padded
        g[0] = f4z; g[1] = f4z;
        #pragma unroll
        for (int i = 2; i < 16; ++i) g[i] = *(const float4*)(zrow + 4*i - 8);
        OUTS48
    }
    #pragma unroll 1
    for (int c = 1; c < 20; ++c) {              // body: fully in-range
        const float* pc = zrow + 48*c - 8;
        #pragma unroll
        for (int i = 0; i < 16; ++i) g[i] = *(const float4*)(pc + 4*i);
        OUTS48
    }
    {   // tail chunk c=20: 40 outputs; zero-pad past t=999
        const float* pc = zrow + 952;
        #pragma unroll
        for (int i = 0; i < 12; ++i) g[i] = *(const float4*)(pc + 4*i);
        g[12] = f4z; g[13] = f4z; g[14] = f4z; g[15] = f4z;
        OUTS40
    }
    #undef GF
    #undef OUT
    #undef OUTS48
    #undef OUTS40
    int row = row0 + r;
    int b = row >> 6, i = row & 63;
    zfeat[(size_t)b * 1024 + h * 64 + i] = cnt * (1.0f / (float)T_);
}

// ---------------- G: logits = z_feat @ fc_w.T + fc_b -----------------------
__global__ __launch_bounds__(256) void k_fc(const float* __restrict__ zfeat, const float* __restrict__ fc_w,
                     const float* __restrict__ fc_b, float* __restrict__ logits) {
    int b = blockIdx.x;
    const float* zf = zfeat + (size_t)b * 1024;
    float a0 = 0.f, a1 = 0.f, a2 = 0.f, a3 = 0.f;
    for (int f = threadIdx.x; f < 1024; f += 256) {
        float z = zf[f];
        a0 += z * fc_w[f];
        a1 += z * fc_w[1024 + f];
        a2 += z * fc_w[2048 + f];
        a3 += z * fc_w[3072 + f];
    }
    __shared__ float red[4][256];
    red[0][threadIdx.x] = a0; red[1][threadIdx.x] = a1;
    red[2][threadIdx.x] = a2; red[3][threadIdx.x] = a3;
    __syncthreads();
    for (int off = 128; off > 0; off >>= 1) {
        if (threadIdx.x < off) {
            red[0][threadIdx.x] += red[0][threadIdx.x + off];
            red[1][threadIdx.x] += red[1][threadIdx.x + off];
            red[2][threadIdx.x] += red[2][threadIdx.x + off];
            red[3][threadIdx.x] += red[3][threadIdx.x + off];
        }
        __syncthreads();
    }
    if (threadIdx.x < 4) logits[b * 4 + threadIdx.x] = red[threadIdx.x][0] + fc_b[threadIdx.x];
}

extern "C" void kernel_launch(void* const* d_in, const int* in_sizes, int n_in,
                              void* d_out, int out_size, void* d_ws, size_t ws_size,
                              hipStream_t stream) {
    (void)in_sizes; (void)n_in; (void)out_size; (void)ws_size;
    const float* x      = (const float*)d_in[0];
    const float* q_w    = (const float*)d_in[1];
    const float* q_b    = (const float*)d_in[2];
    const float* k_w    = (const float*)d_in[3];
    const float* k_b    = (const float*)d_in[4];
    const float* conv_w = (const float*)d_in[5];
    const float* bn_g   = (const float*)d_in[7];
    const float* bn_b   = (const float*)d_in[8];
    const float* fc_w   = (const float*)d_in[9];
    const float* fc_b   = (const float*)d_in[10];

    float* out    = (float*)d_out;
    float* logits = out;                        // 128*4
    float* zfeat  = out + 512;                  // 128*1024
    float* wmat   = out + 512 + 131072;         // 128*64*64

    char* ws      = (char*)d_ws;
    float* energy = (float*)ws;                               // 32 KB
    float* zg     = (float*)(ws + 32768);                     // 32.768 MB
    double* stats = (double*)(ws + 32768 + 32768000);         // 2 KB

    k_energy<<<B_ * N_, 256, 0, stream>>>(x, energy);
    k_zgcn<<<dim3(8, B_), 256, 0, stream>>>(energy, q_w, q_b, k_w, k_b, x, zg, wmat, stats);
    k_autocorr<<<B_ * N_ / 8, 256, 0, stream>>>(zg, stats);
    k_scan<<<B_ * N_ / 16, 256, 0, stream>>>(zg, stats, conv_w, bn_g, bn_b, zfeat);
    k_fc<<<B_, 256, 0, stream>>>(zfeat, fc_w, fc_b, logits);
}

// Round 19
// 182.377 us; speedup vs baseline: 1.1605x; 1.1605x over previous
//
#include <hip/hip_runtime.h>

#define B_ 128
#define N_ 64
#define T_ 1000
#define H_ 16

typedef float v2f __attribute__((ext_vector_type(2)));

// ---------------- A: energy[b,i] = var(x[b,0,i,:], ddof=1) ----------------
__global__ __launch_bounds__(256) void k_energy(const float* __restrict__ x, float* __restrict__ energy) {
    int row = blockIdx.x;                       // b*64 + i
    const float* xr = x + (size_t)row * T_;
    float s = 0.f, s2 = 0.f;
    for (int t4 = threadIdx.x; t4 < 250; t4 += 256) {
        float4 v = ((const float4*)xr)[t4];
        s += v.x + v.y + v.z + v.w;
        s2 += v.x*v.x + v.y*v.y + v.z*v.z + v.w*v.w;
    }
    __shared__ float r1[256], r2[256];
    r1[threadIdx.x] = s; r2[threadIdx.x] = s2;
    __syncthreads();
    for (int off = 128; off > 0; off >>= 1) {
        if (threadIdx.x < off) {
            r1[threadIdx.x] += r1[threadIdx.x + off];
            r2[threadIdx.x] += r2[threadIdx.x + off];
        }
        __syncthreads();
    }
    if (threadIdx.x == 0) {
        float S = r1[0], S2 = r2[0];
        energy[row] = (S2 - S * S / (float)T_) / (float)(T_ - 1);
    }
}

// ------- C (+attn fused): rank-1 attention softmax in-block, then z_gcn ----
#define ZTC 128
__global__ __launch_bounds__(256) void k_zgcn(const float* __restrict__ energy,
        const float* __restrict__ q_w, const float* __restrict__ q_b,
        const float* __restrict__ k_w, const float* __restrict__ k_b,
        const float* __restrict__ x, float* __restrict__ zg,
        float* __restrict__ wmat_out, double* __restrict__ stats) {
    int b = blockIdx.y;
    int t0 = blockIdx.x * ZTC;
    int tid = threadIdx.x;
    if (blockIdx.x == 0 && b == 0 && tid < 163) stats[tid] = 0.0;
    __shared__ __attribute__((aligned(16))) float wsh[64 * 64];
    __shared__ __attribute__((aligned(16))) float xs[64][ZTC];
    __shared__ float en[64];
    float (*red1)[4] = (float(*)[4])&xs[0][0];   // scratch overlay (pre-staging)
    float (*red2)[4] = (float(*)[4])&xs[2][0];
    if (tid < 64) en[tid] = energy[b * 64 + tid];
    __syncthreads();
    float alpha = 0.f, beta = 0.f;
    #pragma unroll
    for (int hh = 0; hh < H_; ++hh) {
        alpha = fmaf(q_w[hh], k_w[hh], alpha);
        beta  = fmaf(q_b[hh], k_w[hh], beta);
    }
    int row = tid >> 2, q = tid & 3;
    float si = 0.25f * fmaf(alpha, en[row], beta);
    float vals[16];
    float m = -3.0e38f;
    #pragma unroll
    for (int k = 0; k < 16; ++k) {
        int j = q * 16 + k;
        float a = si * en[j];
        if (j == row) a = -3.0e38f;
        vals[k] = a;
        m = fmaxf(m, a);
    }
    red1[row][q] = m;
    __syncthreads();
    float m4 = fmaxf(fmaxf(red1[row][0], red1[row][1]), fmaxf(red1[row][2], red1[row][3]));
    float sum = 0.f;
    #pragma unroll
    for (int k = 0; k < 16; ++k) {
        float p = __expf(vals[k] - m4);
        vals[k] = p;
        sum += p;
    }
    red2[row][q] = sum;
    __syncthreads();
    float den = red2[row][0] + red2[row][1] + red2[row][2] + red2[row][3];
    float inv = 1.f / den;
    #pragma unroll
    for (int k = 0; k < 16; ++k) vals[k] *= inv;
    __syncthreads();                             // red scratch dead before xs staging
    #pragma unroll
    for (int k = 0; k < 16; ++k) wsh[row * 64 + q * 16 + k] = vals[k];
    if (blockIdx.x == 0) {
        float* wr = wmat_out + (size_t)b * 4096 + row * 64 + q * 16;
        ((float4*)wr)[0] = float4{vals[0],  vals[1],  vals[2],  vals[3]};
        ((float4*)wr)[1] = float4{vals[4],  vals[5],  vals[6],  vals[7]};
        ((float4*)wr)[2] = float4{vals[8],  vals[9],  vals[10], vals[11]};
        ((float4*)wr)[3] = float4{vals[12], vals[13], vals[14], vals[15]};
    }
    const float* xb = x + (size_t)b * 64 * T_;
    for (int i = tid; i < 2048; i += 256) {
        int jj = i >> 5;
        int c4 = i & 31;
        int tt = t0 + c4 * 4;
        float4 val;
        if (tt + 3 < T_) val = *(const float4*)(xb + jj * T_ + tt);
        else {
            val.x = (tt     < T_) ? xb[jj * T_ + tt]     : 0.f;
            val.y = (tt + 1 < T_) ? xb[jj * T_ + tt + 1] : 0.f;
            val.z = (tt + 2 < T_) ? xb[jj * T_ + tt + 2] : 0.f;
            val.w = (tt + 3 < T_) ? xb[jj * T_ + tt + 3] : 0.f;
        }
        *(float4*)&xs[jj][c4 * 4] = val;
    }
    __syncthreads();
    int gi = tid >> 5, gt = tid & 31;
    int ii0 = gi * 8, tt0 = gt * 4;
    float4 acc[8];
    #pragma unroll
    for (int r = 0; r < 8; ++r) acc[r] = float4{0.f, 0.f, 0.f, 0.f};
    for (int jj = 0; jj < 64; ++jj) {
        float4 xv = *(const float4*)&xs[jj][tt0];
        #pragma unroll
        for (int r = 0; r < 8; ++r) {
            float wv = wsh[(ii0 + r) * 64 + jj];
            acc[r].x += wv * xv.x; acc[r].y += wv * xv.y;
            acc[r].z += wv * xv.z; acc[r].w += wv * xv.w;
        }
    }
    int tt = t0 + tt0;
    #pragma unroll
    for (int r = 0; r < 8; ++r) {
        float4 res = *(const float4*)&xs[ii0 + r][tt0];
        acc[r].x += res.x; acc[r].y += res.y; acc[r].z += res.z; acc[r].w += res.w;
        float* dst = zg + (size_t)b * 64 * T_ + (size_t)(ii0 + r) * T_;
        if (tt + 3 < T_) {
            *(float4*)(dst + tt) = acc[r];
        } else {
            if (tt     < T_) dst[tt]     = acc[r].x;
            if (tt + 1 < T_) dst[tt + 1] = acc[r].y;
            if (tt + 2 < T_) dst[tt + 2] = acc[r].z;
            if (tt + 3 < T_) dst[tt + 3] = acc[r].w;
        }
    }
}

// ------- D: autocorr lags 0..14 + total sum + boundary corrections ---------
__global__ __launch_bounds__(256) void k_autocorr(const float* __restrict__ zg, double* __restrict__ stats) {
    __shared__ float rows[8][1070];             // stride-33 spans, conflict-free
    int row0 = blockIdx.x * 8;
    for (int idx = threadIdx.x; idx < 8 * 1070; idx += 256) {
        int rr = idx / 1070, j = idx - rr * 1070;
        rows[rr][j] = (j < T_) ? zg[(size_t)(row0 + rr) * T_ + j] : 0.f;
    }
    __syncthreads();
    int r = threadIdx.x >> 5, q = threadIdx.x & 31;
    const float* p = &rows[r][0];
    int t = q * 33;
    float w0=p[t+0], w1=p[t+1], w2=p[t+2], w3=p[t+3], w4=p[t+4], w5=p[t+5], w6=p[t+6],
          w7=p[t+7], w8=p[t+8], w9=p[t+9], w10=p[t+10], w11=p[t+11], w12=p[t+12], w13=p[t+13], w14;
    float a0=0.f,a1=0.f,a2=0.f,a3=0.f,a4=0.f,a5=0.f,a6=0.f,a7=0.f,a8=0.f,a9=0.f,
          a10=0.f,a11=0.f,a12=0.f,a13=0.f,a14=0.f, s1=0.f;
    #define ASTEP(wA,wB,wC,wD,wE,wF,wG,wH,wI,wJ,wK,wL,wM,wN,wO, off) { \
        wO = p[t + (off) + 14]; \
        s1 += wA; \
        a0  = fmaf(wA,wA,a0);  a1  = fmaf(wA,wB,a1);  a2  = fmaf(wA,wC,a2);  \
        a3  = fmaf(wA,wD,a3);  a4  = fmaf(wA,wE,a4);  a5  = fmaf(wA,wF,a5);  \
        a6  = fmaf(wA,wG,a6);  a7  = fmaf(wA,wH,a7);  a8  = fmaf(wA,wI,a8);  \
        a9  = fmaf(wA,wJ,a9);  a10 = fmaf(wA,wK,a10); a11 = fmaf(wA,wL,a11); \
        a12 = fmaf(wA,wM,a12); a13 = fmaf(wA,wN,a13); a14 = fmaf(wA,wO,a14); }
    #define AR0(o)  ASTEP(w0,w1,w2,w3,w4,w5,w6,w7,w8,w9,w10,w11,w12,w13,w14, o)
    #define AR1(o)  ASTEP(w1,w2,w3,w4,w5,w6,w7,w8,w9,w10,w11,w12,w13,w14,w0, o)
    #define AR2(o)  ASTEP(w2,w3,w4,w5,w6,w7,w8,w9,w10,w11,w12,w13,w14,w0,w1, o)
    #define AR3(o)  ASTEP(w3,w4,w5,w6,w7,w8,w9,w10,w11,w12,w13,w14,w0,w1,w2, o)
    #define AR4(o)  ASTEP(w4,w5,w6,w7,w8,w9,w10,w11,w12,w13,w14,w0,w1,w2,w3, o)
    #define AR5(o)  ASTEP(w5,w6,w7,w8,w9,w10,w11,w12,w13,w14,w0,w1,w2,w3,w4, o)
    #define AR6(o)  ASTEP(w6,w7,w8,w9,w10,w11,w12,w13,w14,w0,w1,w2,w3,w4,w5, o)
    #define AR7(o)  ASTEP(w7,w8,w9,w10,w11,w12,w13,w14,w0,w1,w2,w3,w4,w5,w6, o)
    #define AR8(o)  ASTEP(w8,w9,w10,w11,w12,w13,w14,w0,w1,w2,w3,w4,w5,w6,w7, o)
    #define AR9(o)  ASTEP(w9,w10,w11,w12,w13,w14,w0,w1,w2,w3,w4,w5,w6,w7,w8, o)
    #define AR10(o) ASTEP(w10,w11,w12,w13,w14,w0,w1,w2,w3,w4,w5,w6,w7,w8,w9, o)
    #define AR11(o) ASTEP(w11,w12,w13,w14,w0,w1,w2,w3,w4,w5,w6,w7,w8,w9,w10, o)
    #define AR12(o) ASTEP(w12,w13,w14,w0,w1,w2,w3,w4,w5,w6,w7,w8,w9,w10,w11, o)
    #define AR13(o) ASTEP(w13,w14,w0,w1,w2,w3,w4,w5,w6,w7,w8,w9,w10,w11,w12, o)
    #define AR14(o) ASTEP(w14,w0,w1,w2,w3,w4,w5,w6,w7,w8,w9,w10,w11,w12,w13, o)
    for (int mi = 0; mi < 2; ++mi) {
        AR0(0) AR1(1) AR2(2) AR3(3) AR4(4) AR5(5) AR6(6) AR7(7)
        AR8(8) AR9(9) AR10(10) AR11(11) AR12(12) AR13(13) AR14(14)
        t += 15;
    }
    AR0(0) AR1(1) AR2(2)                        // 33 total
    #undef ASTEP
    __syncthreads();
    float eacc = 0.f;
    int v = threadIdx.x;
    if (v < 147) {
        int mode, ia, ib;
        if (v < 105) { mode = 0; ia = v / 15; ib = ia + (v % 15); }
        else if (v < 133) {
            int idx = v - 105; int i = 0, len = 7;
            while (idx >= len) { idx -= len; ++i; --len; }
            mode = 2; ia = 993 + i; ib = 993 + i + idx;
        }
        else if (v < 140) { mode = 1; ia = 0; ib = v - 133; }
        else { mode = 1; ia = 993 + (v - 140); ib = 999; }
        for (int rr = 0; rr < 8; ++rr) {
            const float* zr = &rows[rr][0];
            float val;
            if (mode != 1) val = zr[ia] * zr[ib];
            else { val = 0.f; for (int i = ia; i <= ib; ++i) val += zr[i]; }
            eacc += val;
        }
    }
    __syncthreads();
    float* red = &rows[0][0];
    int tid = threadIdx.x;
    red[tid*17+0]=a0;  red[tid*17+1]=a1;  red[tid*17+2]=a2;  red[tid*17+3]=a3;
    red[tid*17+4]=a4;  red[tid*17+5]=a5;  red[tid*17+6]=a6;  red[tid*17+7]=a7;
    red[tid*17+8]=a8;  red[tid*17+9]=a9;  red[tid*17+10]=a10; red[tid*17+11]=a11;
    red[tid*17+12]=a12; red[tid*17+13]=a13; red[tid*17+14]=a14; red[tid*17+15]=s1;
    __syncthreads();
    for (int off = 128; off > 0; off >>= 1) {
        if (tid < off)
            for (int k = 0; k < 16; ++k) red[tid*17+k] += red[(tid+off)*17+k];
        __syncthreads();
    }
    if (tid < 16) atomicAdd(&stats[tid], (double)red[tid]);
    if (v < 147) atomicAdd(&stats[16 + v], (double)eacc);
}

// ------- F: finalize(in-block) + dual-copy LDS + rotating b64 pairs --------
// 16 rows x 16 ch per block; T in 21 chunks of 48 (last 40).
// in_s[j]=z(48c-8+j); in2[j+1]=z(48c-8+j) -> every tap pair is an aligned
// ds_read_b64; rotating E0..E7/O0..O6 regs give ~1 LDS read per output.
__global__ __launch_bounds__(256) void k_scan(const float* __restrict__ zg,
        const double* __restrict__ stats, const float* __restrict__ conv_w,
        const float* __restrict__ gamma, const float* __restrict__ beta,
        float* __restrict__ zfeat) {
    __shared__ float in_s[2][16][68];
    __shared__ float in2[2][16][70];
    __shared__ float scsh_s[256];
    int tid = threadIdx.x;
    int h = tid & 15, r = tid >> 4;
    int row0 = blockIdx.x * 16;
    if (tid < 16) {                             // finalize BN -> folded taps
        int hh = tid;
        const double M = (double)(B_ * N_) * (double)T_;
        double w[15];
        #pragma unroll
        for (int k = 0; k < 15; ++k) w[k] = (double)conv_w[hh * 15 + k];
        double SA = stats[15];
        const double* HP  = stats + 16;
        const double* TP  = stats + 16 + 105;
        const double* PRE = stats + 16 + 133;
        const double* SUF = stats + 16 + 140;
        double so = 0.0;
        #pragma unroll
        for (int k = 0; k < 15; ++k) {
            double U = SA;
            if (k < 7)      U -= SUF[k];
            else if (k > 7) U -= PRE[k - 8];
            so += w[k] * U;
        }
        double mean_o = so / M;
        double q = 0.0;
        #pragma unroll
        for (int k = 0; k < 15; ++k)
        #pragma unroll
        for (int k2 = 0; k2 < 15; ++k2) {
            int a = (k < k2) ? k : k2;
            int d = (k < k2) ? (k2 - k) : (k - k2);
            double G = stats[d];
            if (a >= 8)
                for (int i = 0; i <= a - 8; ++i) G -= HP[i * 15 + d];
            if (a + d <= 6)
                for (int i = a + 993; i <= 999 - d; ++i) {
                    int ip = i - 993;
                    G -= TP[ip * 7 - ip * (ip - 1) / 2 + d];
                }
            q += w[k] * w[k2] * G;
        }
        double var = q / M - mean_o * mean_o;
        double sc = (double)gamma[hh] / sqrt(var + 1e-5);
        scsh_s[240 + hh] = (float)((double)beta[hh] - mean_o * sc);
        #pragma unroll
        for (int k = 0; k < 15; ++k) scsh_s[hh * 15 + k] = (float)(w[k] * sc);
    }
    __syncthreads();
    float c0 = scsh_s[h*15+0],  c1 = scsh_s[h*15+1],  c2 = scsh_s[h*15+2],  c3 = scsh_s[h*15+3];
    float c4 = scsh_s[h*15+4],  c5 = scsh_s[h*15+5],  c6 = scsh_s[h*15+6],  c7 = scsh_s[h*15+7];
    float c8 = scsh_s[h*15+8],  c9 = scsh_s[h*15+9],  c10 = scsh_s[h*15+10], c11 = scsh_s[h*15+11];
    float c12 = scsh_s[h*15+12], c13 = scsh_s[h*15+13], c14 = scsh_s[h*15+14];
    float sh = scsh_s[240 + h];
    v2f d0 = {c0,c0},  d1 = {c1,c1},  d2 = {c2,c2},  d3 = {c3,c3},  d4 = {c4,c4};
    v2f d5 = {c5,c5},  d6 = {c6,c6},  d7 = {c7,c7},  d8 = {c8,c8},  d9 = {c9,c9};
    v2f d10 = {c10,c10}, d11 = {c11,c11}, d12 = {c12,c12}, d13 = {c13,c13}, d14 = {c14,c14};
    v2f shp2 = {sh, sh}, zr2 = {0.f, 0.f};
    float u = 2.f, cnt = 0.f;
    float ld0, ld1, ld2, ld3;
    int su = tid & 63, sr = tid >> 6;

    #define STAGE_LOAD(cc) { \
        int g = (cc) * 48 - 8 + su; \
        bool ok = (g >= 0 && g < T_); \
        const float* zp_ = zg + (size_t)(row0 + sr) * T_ + g; \
        ld0 = ok ? zp_[0] : 0.f; \
        ld1 = ok ? zp_[4 * T_] : 0.f; \
        ld2 = ok ? zp_[8 * T_] : 0.f; \
        ld3 = ok ? zp_[12 * T_] : 0.f; }

    #define STAGE_WRITE(db) { \
        in_s[db][sr][su]       = ld0;  in2[db][sr][su + 1]       = ld0; \
        in_s[db][sr + 4][su]   = ld1;  in2[db][sr + 4][su + 1]   = ld1; \
        in_s[db][sr + 8][su]   = ld2;  in2[db][sr + 8][su + 1]   = ld2; \
        in_s[db][sr + 12][su]  = ld3;  in2[db][sr + 12][su + 1]  = ld3; }

    #define PKF(acc, cc, xp)  asm("v_pk_fma_f32 %0, %1, %2, %0" : "+v"(acc) : "v"(cc), "v"(xp))
    #define PKADD(dd, aa, bb) asm("v_pk_add_f32 %0, %1, %2" : "=v"(dd) : "v"(aa), "v"(bb))

    #define EP(n) (*(const v2f*)(p2 + (n) + 1))   // odd n -> even in2 offset
    #define OP(n) (*(const v2f*)(pN + (n)))       // even n

    #define PSTEP(Ea,Eb,Ec,Ed,Ee,Ef,Eg,Eh, Oa,Ob,Oc,Od,Oe,Of,Og, mm) { \
        Eh = EP(2*(mm)+15); Og = OP(2*(mm)+14); \
        v2f vA = shp2, vB = zr2; \
        PKF(vA, d0,  Ea); PKF(vB, d1,  Oa); \
        PKF(vA, d2,  Eb); PKF(vB, d3,  Ob); \
        PKF(vA, d4,  Ec); PKF(vB, d5,  Oc); \
        PKF(vA, d6,  Ed); PKF(vB, d7,  Od); \
        PKF(vA, d8,  Ee); PKF(vB, d9,  Oe); \
        PKF(vA, d10, Ef); PKF(vB, d11, Of); \
        PKF(vA, d12, Eg); PKF(vB, d13, Og); \
        PKF(vA, d14, Eh); \
        v2f vz; PKADD(vz, vA, vB); \
        float pe0 = fmaxf(vz.x, 0.f) + __expf(fminf(vz.x, 0.f)); \
        u = fmaf(0.5f, u, pe0); \
        float sp0 = (u > 2.5f) ? 1.f : 0.f; cnt += sp0; u = fmaf(-0.5f, sp0, u); \
        float pe1 = fmaxf(vz.y, 0.f) + __expf(fminf(vz.y, 0.f)); \
        u = fmaf(0.5f, u, pe1); \
        float sp1 = (u > 2.5f) ? 1.f : 0.f; cnt += sp1; u = fmaf(-0.5f, sp1, u); }

    #define PRELOAD \
        v2f E0=EP(1), E1=EP(3), E2=EP(5), E3=EP(7), E4=EP(9), E5=EP(11), E6=EP(13), E7; \
        v2f O0=OP(2), O1=OP(4), O2=OP(6), O3=OP(8), O4=OP(10), O5=OP(12), O6;

    #define PS20 \
        PSTEP(E0,E1,E2,E3,E4,E5,E6,E7, O0,O1,O2,O3,O4,O5,O6, 0) \
        PSTEP(E1,E2,E3,E4,E5,E6,E7,E0, O1,O2,O3,O4,O5,O6,O0, 1) \
        PSTEP(E2,E3,E4,E5,E6,E7,E0,E1, O2,O3,O4,O5,O6,O0,O1, 2) \
        PSTEP(E3,E4,E5,E6,E7,E0,E1,E2, O3,O4,O5,O6,O0,O1,O2, 3) \
        PSTEP(E4,E5,E6,E7,E0,E1,E2,E3, O4,O5,O6,O0,O1,O2,O3, 4) \
        PSTEP(E5,E6,E7,E0,E1,E2,E3,E4, O5,O6,O0,O1,O2,O3,O4, 5) \
        PSTEP(E6,E7,E0,E1,E2,E3,E4,E5, O6,O0,O1,O2,O3,O4,O5, 6) \
        PSTEP(E7,E0,E1,E2,E3,E4,E5,E6, O0,O1,O2,O3,O4,O5,O6, 7) \
        PSTEP(E0,E1,E2,E3,E4,E5,E6,E7, O1,O2,O3,O4,O5,O6,O0, 8) \
        PSTEP(E1,E2,E3,E4,E5,E6,E7,E0, O2,O3,O4,O5,O6,O0,O1, 9) \
        PSTEP(E2,E3,E4,E5,E6,E7,E0,E1, O3,O4,O5,O6,O0,O1,O2, 10) \
        PSTEP(E3,E4,E5,E6,E7,E0,E1,E2, O4,O5,O6,O0,O1,O2,O3, 11) \
        PSTEP(E4,E5,E6,E7,E0,E1,E2,E3, O5,O6,O0,O1,O2,O3,O4, 12) \
        PSTEP(E5,E6,E7,E0,E1,E2,E3,E4, O6,O0,O1,O2,O3,O4,O5, 13) \
        PSTEP(E6,E7,E0,E1,E2,E3,E4,E5, O0,O1,O2,O3,O4,O5,O6, 14) \
        PSTEP(E7,E0,E1,E2,E3,E4,E5,E6, O1,O2,O3,O4,O5,O6,O0, 15) \
        PSTEP(E0,E1,E2,E3,E4,E5,E6,E7, O2,O3,O4,O5,O6,O0,O1, 16) \
        PSTEP(E1,E2,E3,E4,E5,E6,E7,E0, O3,O4,O5,O6,O0,O1,O2, 17) \
        PSTEP(E2,E3,E4,E5,E6,E7,E0,E1, O4,O5,O6,O0,O1,O2,O3, 18) \
        PSTEP(E3,E4,E5,E6,E7,E0,E1,E2, O5,O6,O0,O1,O2,O3,O4, 19)

    #define PS24 PS20 \
        PSTEP(E4,E5,E6,E7,E0,E1,E2,E3, O6,O0,O1,O2,O3,O4,O5, 20) \
        PSTEP(E5,E6,E7,E0,E1,E2,E3,E4, O0,O1,O2,O3,O4,O5,O6, 21) \
        PSTEP(E6,E7,E0,E1,E2,E3,E4,E5, O1,O2,O3,O4,O5,O6,O0, 22) \
        PSTEP(E7,E0,E1,E2,E3,E4,E5,E6, O2,O3,O4,O5,O6,O0,O1, 23)

    STAGE_LOAD(0)
    STAGE_WRITE(0)
    __syncthreads();
    int buf = 0;
    #pragma unroll 1
    for (int c = 0; c < 20; ++c) {
        STAGE_LOAD(c + 1)                       // issue early (T14)
        {
            const float* pN = &in_s[buf][r][0];
            const float* p2 = &in2[buf][r][0];
            PRELOAD
            PS24
        }
        STAGE_WRITE(buf ^ 1)                    // write late (after compute)
        __syncthreads();
        buf ^= 1;
    }
    {   // tail chunk c=20: 40 outputs = 20 pairs
        const float* pN = &in_s[buf][r][0];
        const float* p2 = &in2[buf][r][0];
        PRELOAD
        PS20
    }
    #undef STAGE_LOAD
    #undef STAGE_WRITE
    #undef PKF
    #undef PKADD
    #undef EP
    #undef OP
    #undef PSTEP
    #undef PRELOAD
    #undef PS20
    #undef PS24
    int row = row0 + r;
    int b = row >> 6, i = row & 63;
    zfeat[(size_t)b * 1024 + h * 64 + i] = cnt * (1.0f / (float)T_);
}

// ---------------- G: logits = z_feat @ fc_w.T + fc_b -----------------------
__global__ __launch_bounds__(256) void k_fc(const float* __restrict__ zfeat, const float* __restrict__ fc_w,
                     const float* __restrict__ fc_b, float* __restrict__ logits) {
    int b = blockIdx.x;
    const float* zf = zfeat + (size_t)b * 1024;
    float a0 = 0.f, a1 = 0.f, a2 = 0.f, a3 = 0.f;
    for (int f = threadIdx.x; f < 1024; f += 256) {
        float z = zf[f];
        a0 += z * fc_w[f];
        a1 += z * fc_w[1024 + f];
        a2 += z * fc_w[2048 + f];
        a3 += z * fc_w[3072 + f];
    }
    __shared__ float red[4][256];
    red[0][threadIdx.x] = a0; red[1][threadIdx.x] = a1;
    red[2][threadIdx.x] = a2; red[3][threadIdx.x] = a3;
    __syncthreads();
    for (int off = 128; off > 0; off >>= 1) {
        if (threadIdx.x < off) {
            red[0][threadIdx.x] += red[0][threadIdx.x + off];
            red[1][threadIdx.x] += red[1][threadIdx.x + off];
            red[2][threadIdx.x] += red[2][threadIdx.x + off];
            red[3][threadIdx.x] += red[3][threadIdx.x + off];
        }
        __syncthreads();
    }
    if (threadIdx.x < 4) logits[b * 4 + threadIdx.x] = red[threadIdx.x][0] + fc_b[threadIdx.x];
}

extern "C" void kernel_launch(void* const* d_in, const int* in_sizes, int n_in,
                              void* d_out, int out_size, void* d_ws, size_t ws_size,
                              hipStream_t stream) {
    (void)in_sizes; (void)n_in; (void)out_size; (void)ws_size;
    const float* x      = (const float*)d_in[0];
    const float* q_w    = (const float*)d_in[1];
    const float* q_b    = (const float*)d_in[2];
    const float* k_w    = (const float*)d_in[3];
    const float* k_b    = (const float*)d_in[4];
    const float* conv_w = (const float*)d_in[5];
    const float* bn_g   = (const float*)d_in[7];
    const float* bn_b   = (const float*)d_in[8];
    const float* fc_w   = (const float*)d_in[9];
    const float* fc_b   = (const float*)d_in[10];

    float* out    = (float*)d_out;
    float* logits = out;                        // 128*4
    float* zfeat  = out + 512;                  // 128*1024
    float* wmat   = out + 512 + 131072;         // 128*64*64

    char* ws      = (char*)d_ws;
    float* energy = (float*)ws;                               // 32 KB
    float* zg     = (float*)(ws + 32768);                     // 32.768 MB
    double* stats = (double*)(ws + 32768 + 32768000);         // 2 KB

    k_energy<<<B_ * N_, 256, 0, stream>>>(x, energy);
    k_zgcn<<<dim3(8, B_), 256, 0, stream>>>(energy, q_w, q_b, k_w, k_b, x, zg, wmat, stats);
    k_autocorr<<<B_ * N_ / 8, 256, 0, stream>>>(zg, stats);
    k_scan<<<B_ * N_ / 16, 256, 0, stream>>>(zg, stats, conv_w, bn_g, bn_b, zfeat);
    k_fc<<<B_, 256, 0, stream>>>(zfeat, fc_w, fc_b, logits);
}